// Round 1
// baseline (87.971 us; speedup 1.0000x reference)
//
#include <hip/hip_runtime.h>
#include <hip/hip_bf16.h>

#define NN 8192
#define DD 128
#define BM 128
#define BN 128
#define NTB (NN / BN)   // 64 tile columns

using floatx4 = __attribute__((ext_vector_type(4))) float;
using shortx8 = __attribute__((ext_vector_type(8))) short;

__device__ __forceinline__ unsigned bf16pair(float lo, float hi) {
    unsigned ulo = __float_as_uint(lo);
    ulo = (ulo + 0x7FFFu + ((ulo >> 16) & 1u)) >> 16;          // RNE bf16, low half
    unsigned uhi = __float_as_uint(hi);
    uhi = (uhi + 0x7FFFu + ((uhi >> 16) & 1u)) & 0xFFFF0000u;  // RNE bf16, high half
    return uhi | ulo;
}

// ---- per-row squared norms of x and y ----
__global__ void norms_kernel(const float* __restrict__ x, const float* __restrict__ y,
                             float* __restrict__ xx, float* __restrict__ yy) {
    const int wv = threadIdx.x >> 6, lane = threadIdx.x & 63;
    const int row = blockIdx.x * 4 + wv;
    const float2 a = reinterpret_cast<const float2*>(x)[row * (DD / 2) + lane];
    const float2 b = reinterpret_cast<const float2*>(y)[row * (DD / 2) + lane];
    float sx = a.x * a.x + a.y * a.y;
    float sy = b.x * b.x + b.y * b.y;
    #pragma unroll
    for (int off = 32; off; off >>= 1) {
        sx += __shfl_down(sx, off);
        sy += __shfl_down(sy, off);
    }
    if (lane == 0) { xx[row] = sx; yy[row] = sy; }
}

// ---- fused GEMM + log-Cauchy epilogue, per-block partial sums ----
__global__ __launch_bounds__(256, 2) void
tile_kernel(const float* __restrict__ x, const float* __restrict__ y,
            const float* __restrict__ xx, const float* __restrict__ yy,
            float* __restrict__ partials) {
    __shared__ __align__(16) short As[BM * DD];
    __shared__ __align__(16) short Bs[BN * DD];
    __shared__ float red[4][4];

    const int bx = blockIdx.x % NTB;
    const int by = blockIdx.x / NTB;
    const int tid = threadIdx.x;

    // stage + convert f32 -> bf16, XOR-swizzled LDS layout
    {
        const int ch = tid & 31;   // 16B (4-float) chunk within a row
        const int r0 = tid >> 5;   // 0..7
        char* Ab = reinterpret_cast<char*>(As);
        char* Bb = reinterpret_cast<char*>(Bs);
        #pragma unroll
        for (int p = 0; p < 16; ++p) {
            const int row = p * 8 + r0;
            const float4 va = *reinterpret_cast<const float4*>(x + (by * BM + row) * DD + ch * 4);
            const float4 vb = *reinterpret_cast<const float4*>(y + (bx * BN + row) * DD + ch * 4);
            const int boff = (row * 256 + ch * 8) ^ ((row & 7) << 4);
            uint2 pa, pb;
            pa.x = bf16pair(va.x, va.y); pa.y = bf16pair(va.z, va.w);
            pb.x = bf16pair(vb.x, vb.y); pb.y = bf16pair(vb.z, vb.w);
            *reinterpret_cast<uint2*>(Ab + boff) = pa;
            *reinterpret_cast<uint2*>(Bb + boff) = pb;
        }
    }
    __syncthreads();

    const int wv = tid >> 6;
    const int lane = tid & 63;
    const int wr = (wv >> 1) * 64;   // wave row offset in tile
    const int wc = (wv & 1) * 64;    // wave col offset in tile
    const int l15 = lane & 15;
    const int kq = lane >> 4;        // k-quarter: 8 bf16 each

    floatx4 acc[4][4];
    #pragma unroll
    for (int m = 0; m < 4; ++m)
        #pragma unroll
        for (int n = 0; n < 4; ++n)
            acc[m][n] = (floatx4){0.f, 0.f, 0.f, 0.f};

    const char* Ab = reinterpret_cast<const char*>(As);
    const char* Bb = reinterpret_cast<const char*>(Bs);
    #pragma unroll
    for (int kk = 0; kk < 4; ++kk) {
        const int kbyte = kk * 64 + kq * 16;
        shortx8 a[4], b[4];
        #pragma unroll
        for (int m = 0; m < 4; ++m) {
            const int ra = wr + m * 16 + l15;
            a[m] = *reinterpret_cast<const shortx8*>(Ab + ((ra * 256 + kbyte) ^ ((ra & 7) << 4)));
            const int rb = wc + m * 16 + l15;
            b[m] = *reinterpret_cast<const shortx8*>(Bb + ((rb * 256 + kbyte) ^ ((rb & 7) << 4)));
        }
        #pragma unroll
        for (int m = 0; m < 4; ++m)
            #pragma unroll
            for (int n = 0; n < 4; ++n)
                acc[m][n] = __builtin_amdgcn_mfma_f32_16x16x32_bf16(a[m], b[n], acc[m][n], 0, 0, 0);
    }

    // fused epilogue: logit = -log(1+sq), e = 1/(1+sq) = exp(logit)
    float s_log = 0.f, s_exp = 0.f, p_log = 0.f, p_exp = 0.f;
    const int rbase = by * BM + wr + kq * 4;
    const int cbase = bx * BN + wc + l15;
    #pragma unroll
    for (int m = 0; m < 4; ++m) {
        float xv[4];
        #pragma unroll
        for (int j = 0; j < 4; ++j) xv[j] = xx[rbase + m * 16 + j];
        #pragma unroll
        for (int n = 0; n < 4; ++n) {
            const int gcol = cbase + n * 16;
            const float yyv = yy[gcol];
            #pragma unroll
            for (int j = 0; j < 4; ++j) {
                const float sq0 = xv[j] + yyv - 2.0f * acc[m][n][j];
                const float t = 1.0f + fmaxf(sq0, 0.0f);
                const float lg = -__logf(t);
                const float e = __builtin_amdgcn_rcpf(t);
                s_log += lg;
                s_exp += e;
                if (rbase + m * 16 + j == gcol) { p_log += lg; p_exp += e; }
            }
        }
    }

    #pragma unroll
    for (int off = 32; off; off >>= 1) {
        s_log += __shfl_down(s_log, off);
        s_exp += __shfl_down(s_exp, off);
        p_log += __shfl_down(p_log, off);
        p_exp += __shfl_down(p_exp, off);
    }
    if (lane == 0) {
        red[wv][0] = s_log; red[wv][1] = s_exp; red[wv][2] = p_log; red[wv][3] = p_exp;
    }
    __syncthreads();
    if (tid < 4) {
        const float v = red[0][tid] + red[1][tid] + red[2][tid] + red[3][tid];
        partials[blockIdx.x * 4 + tid] = v;
    }
}

// ---- final reduction + the 4 scalar outputs ----
__global__ void finalize_kernel(const float* __restrict__ partials, int nblocks,
                                float* __restrict__ out) {
    float4 v = {0.f, 0.f, 0.f, 0.f};
    for (int i = threadIdx.x; i < nblocks; i += 256) {
        const float4 p = reinterpret_cast<const float4*>(partials)[i];
        v.x += p.x; v.y += p.y; v.z += p.z; v.w += p.w;
    }
    #pragma unroll
    for (int off = 32; off; off >>= 1) {
        v.x += __shfl_down(v.x, off);
        v.y += __shfl_down(v.y, off);
        v.z += __shfl_down(v.z, off);
        v.w += __shfl_down(v.w, off);
    }
    __shared__ float red[4][4];
    const int wv = threadIdx.x >> 6, lane = threadIdx.x & 63;
    if (lane == 0) { red[wv][0] = v.x; red[wv][1] = v.y; red[wv][2] = v.z; red[wv][3] = v.w; }
    __syncthreads();
    if (threadIdx.x == 0) {
        double Sl = 0, Se = 0, Pl = 0, Pe = 0;
        for (int w = 0; w < 4; ++w) {
            Sl += red[w][0]; Se += red[w][1]; Pl += red[w][2]; Pe += red[w][3];
        }
        const double Nd = (double)NN;
        const double Md = Nd * (Nd - 1.0);
        const double mean_pos = Pl / Nd;
        const double mean_neg = (Sl - Pl) / Md;
        const double sumexp_neg = Se - Pe;
        const double lb = log(sumexp_neg) - log(Md);
        const double repulsion = sumexp_neg / (Md * exp(lb));
        const double loss = -(mean_pos - lb) + repulsion;   // EMBED_DECAY == 0
        out[0] = (float)mean_pos;
        out[1] = (float)mean_neg;
        out[2] = (float)lb;
        out[3] = (float)loss;
    }
}

extern "C" void kernel_launch(void* const* d_in, const int* in_sizes, int n_in,
                              void* d_out, int out_size, void* d_ws, size_t ws_size,
                              hipStream_t stream) {
    (void)in_sizes; (void)n_in; (void)out_size; (void)ws_size;
    const float* zx = (const float*)d_in[0];
    const float* zy = (const float*)d_in[1];
    float* out = (float*)d_out;
    float* ws = (float*)d_ws;
    float* xx = ws;                 // [NN]
    float* yy = ws + NN;            // [NN]
    float* partials = ws + 2 * NN;  // [NTB*NTB*4]

    hipLaunchKernelGGL(norms_kernel, dim3(NN / 4), dim3(256), 0, stream, zx, zy, xx, yy);
    hipLaunchKernelGGL(tile_kernel, dim3(NTB * NTB), dim3(256), 0, stream, zx, zy, xx, yy, partials);
    hipLaunchKernelGGL(finalize_kernel, dim3(1), dim3(256), 0, stream, partials, NTB * NTB, out);
}

// Round 2
// 53.863 us; speedup vs baseline: 1.6332x; 1.6332x over previous
//
#include <hip/hip_runtime.h>
#include <hip/hip_bf16.h>

#define NN 8192
#define DD 128
#define BM 128
#define BN 128
#define NTB (NN / BN)   // 64 tile columns

using floatx4 = __attribute__((ext_vector_type(4))) float;
using shortx8 = __attribute__((ext_vector_type(8))) short;
typedef unsigned short ushort_t;

typedef __attribute__((address_space(1))) const unsigned GlbU32;
typedef __attribute__((address_space(3))) unsigned LdsU32;

__device__ __forceinline__ unsigned bf16pair(float lo, float hi) {
    unsigned ulo = __float_as_uint(lo);
    ulo = (ulo + 0x7FFFu + ((ulo >> 16) & 1u)) >> 16;          // RNE bf16, low half
    unsigned uhi = __float_as_uint(hi);
    uhi = (uhi + 0x7FFFu + ((uhi >> 16) & 1u)) & 0xFFFF0000u;  // RNE bf16, high half
    return uhi | ulo;
}

// ---- prep: f32 -> bf16 (row-swizzled for global_load_lds) + squared norms ----
// Swizzle: 16B-chunk c of row r stored at chunk position c ^ (r & 7), so that a
// LINEAR global_load_lds DMA produces the XOR-swizzled LDS layout the MFMA
// reads expect (rule #21: inverse-swizzled source + swizzled read).
__global__ void prep_kernel(const float* __restrict__ x, const float* __restrict__ y,
                            ushort_t* __restrict__ xb, ushort_t* __restrict__ yb,
                            float* __restrict__ xx, float* __restrict__ yy) {
    const int tid = threadIdx.x;
    const int r = blockIdx.x * 16 + (tid >> 4);
    const int c = tid & 15;
    const int sc = c ^ (r & 7);

    {
        const float4* xv = reinterpret_cast<const float4*>(x) + r * 32 + c * 2;
        const float4 a = xv[0], b = xv[1];
        uint4 u;
        u.x = bf16pair(a.x, a.y); u.y = bf16pair(a.z, a.w);
        u.z = bf16pair(b.x, b.y); u.w = bf16pair(b.z, b.w);
        reinterpret_cast<uint4*>(xb)[r * 16 + sc] = u;
        float s = a.x*a.x + a.y*a.y + a.z*a.z + a.w*a.w
                + b.x*b.x + b.y*b.y + b.z*b.z + b.w*b.w;
        #pragma unroll
        for (int off = 8; off; off >>= 1) s += __shfl_xor(s, off);
        if (c == 0) xx[r] = s;
    }
    {
        const float4* yv = reinterpret_cast<const float4*>(y) + r * 32 + c * 2;
        const float4 a = yv[0], b = yv[1];
        uint4 u;
        u.x = bf16pair(a.x, a.y); u.y = bf16pair(a.z, a.w);
        u.z = bf16pair(b.x, b.y); u.w = bf16pair(b.z, b.w);
        reinterpret_cast<uint4*>(yb)[r * 16 + sc] = u;
        float s = a.x*a.x + a.y*a.y + a.z*a.z + a.w*a.w
                + b.x*b.x + b.y*b.y + b.z*b.z + b.w*b.w;
        #pragma unroll
        for (int off = 8; off; off >>= 1) s += __shfl_xor(s, off);
        if (c == 0) yy[r] = s;
    }
}

template<bool DIAG>
__device__ __forceinline__ void epilogue(const floatx4 (&acc)[4][2],
                                         const float* xs, const float* ys,
                                         int r0, int c0,
                                         float& s_l2, float& s_e, float& p_l2, float& p_e) {
    #pragma unroll
    for (int m = 0; m < 4; ++m) {
        float xv1[4];
        #pragma unroll
        for (int j = 0; j < 4; ++j) xv1[j] = xs[r0 + m * 16 + j] + 1.0f;
        #pragma unroll
        for (int n = 0; n < 2; ++n) {
            const float yv = ys[c0 + n * 16];
            #pragma unroll
            for (int j = 0; j < 4; ++j) {
                // t = 1 + max(sq,0) = max(xx + yy + 1 - 2*dot, 1)
                const float t = fmaxf(fmaf(-2.0f, acc[m][n][j], xv1[j] + yv), 1.0f);
                const float l2 = __builtin_amdgcn_logf(t);   // log2(t)
                const float e  = __builtin_amdgcn_rcpf(t);   // 1/t = exp(logit)
                s_l2 += l2; s_e += e;
                if (DIAG && (r0 + m * 16 + j == c0 + n * 16)) { p_l2 += l2; p_e += e; }
            }
        }
    }
}

// ---- fused GEMM + log-Cauchy epilogue, per-block partial sums ----
__global__ __launch_bounds__(512, 4) void
tile_kernel(const ushort_t* __restrict__ xb, const ushort_t* __restrict__ yb,
            const float* __restrict__ xx, const float* __restrict__ yy,
            float* __restrict__ partials) {
    __shared__ __align__(16) ushort_t As[BM * DD];
    __shared__ __align__(16) ushort_t Bs[BN * DD];
    __shared__ float xs[BM], ys[BN];
    __shared__ float red[8][4];

    const int bx = blockIdx.x & (NTB - 1);
    const int by = blockIdx.x / NTB;
    const int tid = threadIdx.x;
    const int wv = tid >> 6, lane = tid & 63;

    if (tid < 128)      xs[tid] = xx[by * BM + tid];
    else if (tid < 256) ys[tid - 128] = yy[bx * BN + (tid - 128)];

    // DMA-stage tiles: wave wv stages 16 rows of A and B (linear dest, source
    // already swizzled). Each call: 64 lanes x 16B = 4 rows.
    {
        const int rbase = wv * 16;
        const int lr = (lane >> 4);
        const int lc = (lane & 15) * 8;
        #pragma unroll
        for (int it = 0; it < 4; ++it) {
            const int row = rbase + it * 4 + lr;
            const ushort_t* ga = xb + (size_t)(by * BM + row) * DD + lc;
            const ushort_t* gb = yb + (size_t)(bx * BN + row) * DD + lc;
            __builtin_amdgcn_global_load_lds((GlbU32*)ga, (LdsU32*)(As + (rbase + it * 4) * DD), 16, 0, 0);
            __builtin_amdgcn_global_load_lds((GlbU32*)gb, (LdsU32*)(Bs + (rbase + it * 4) * DD), 16, 0, 0);
        }
    }
    __syncthreads();

    const int wr = (wv >> 2) * 64;   // 2 wave-rows
    const int wc = (wv & 3) * 32;    // 4 wave-cols
    const int l15 = lane & 15;
    const int kq = lane >> 4;

    floatx4 acc[4][2];
    #pragma unroll
    for (int m = 0; m < 4; ++m)
        #pragma unroll
        for (int n = 0; n < 2; ++n)
            acc[m][n] = (floatx4){0.f, 0.f, 0.f, 0.f};

    const char* Ab = reinterpret_cast<const char*>(As);
    const char* Bb = reinterpret_cast<const char*>(Bs);
    #pragma unroll
    for (int kk = 0; kk < 4; ++kk) {
        const int kbyte = kk * 64 + kq * 16;
        shortx8 a[4], b[2];
        #pragma unroll
        for (int m = 0; m < 4; ++m) {
            const int ra = wr + m * 16 + l15;
            a[m] = *reinterpret_cast<const shortx8*>(Ab + ((ra * 256 + kbyte) ^ ((ra & 7) << 4)));
        }
        #pragma unroll
        for (int n = 0; n < 2; ++n) {
            const int rb = wc + n * 16 + l15;
            b[n] = *reinterpret_cast<const shortx8*>(Bb + ((rb * 256 + kbyte) ^ ((rb & 7) << 4)));
        }
        #pragma unroll
        for (int m = 0; m < 4; ++m)
            #pragma unroll
            for (int n = 0; n < 2; ++n)
                acc[m][n] = __builtin_amdgcn_mfma_f32_16x16x32_bf16(a[m], b[n], acc[m][n], 0, 0, 0);
    }

    float s_l2 = 0.f, s_e = 0.f, p_l2 = 0.f, p_e = 0.f;
    const int r0 = wr + kq * 4;
    const int c0 = wc + l15;
    if (bx == by) epilogue<true >(acc, xs, ys, r0, c0, s_l2, s_e, p_l2, p_e);
    else          epilogue<false>(acc, xs, ys, r0, c0, s_l2, s_e, p_l2, p_e);

    #pragma unroll
    for (int off = 32; off; off >>= 1) {
        s_l2 += __shfl_down(s_l2, off);
        s_e  += __shfl_down(s_e,  off);
        p_l2 += __shfl_down(p_l2, off);
        p_e  += __shfl_down(p_e,  off);
    }
    if (lane == 0) {
        red[wv][0] = s_l2; red[wv][1] = s_e; red[wv][2] = p_l2; red[wv][3] = p_e;
    }
    __syncthreads();
    if (tid < 4) {
        float v = 0.f;
        #pragma unroll
        for (int w = 0; w < 8; ++w) v += red[w][tid];
        partials[blockIdx.x * 4 + tid] = v;
    }
}

// ---- final reduction + the 4 scalar outputs ----
__global__ void finalize_kernel(const float* __restrict__ partials, int nblocks,
                                float* __restrict__ out) {
    float4 v = {0.f, 0.f, 0.f, 0.f};
    for (int i = threadIdx.x; i < nblocks; i += 256) {
        const float4 p = reinterpret_cast<const float4*>(partials)[i];
        v.x += p.x; v.y += p.y; v.z += p.z; v.w += p.w;
    }
    #pragma unroll
    for (int off = 32; off; off >>= 1) {
        v.x += __shfl_down(v.x, off);
        v.y += __shfl_down(v.y, off);
        v.z += __shfl_down(v.z, off);
        v.w += __shfl_down(v.w, off);
    }
    __shared__ float red[4][4];
    const int wv = threadIdx.x >> 6, lane = threadIdx.x & 63;
    if (lane == 0) { red[wv][0] = v.x; red[wv][1] = v.y; red[wv][2] = v.z; red[wv][3] = v.w; }
    __syncthreads();
    if (threadIdx.x == 0) {
        double Sl2 = 0, Se = 0, Pl2 = 0, Pe = 0;
        for (int w = 0; w < 4; ++w) {
            Sl2 += red[w][0]; Se += red[w][1]; Pl2 += red[w][2]; Pe += red[w][3];
        }
        const double LN2 = 0.6931471805599453;
        const double Sl = -LN2 * Sl2;   // sum of logits over all pairs (natural log)
        const double Pl = -LN2 * Pl2;   // sum over diagonal
        const double Nd = (double)NN;
        const double Md = Nd * (Nd - 1.0);
        const double mean_pos = Pl / Nd;
        const double mean_neg = (Sl - Pl) / Md;
        const double sumexp_neg = Se - Pe;
        const double lb = log(sumexp_neg) - log(Md);
        const double repulsion = sumexp_neg / (Md * exp(lb));
        const double loss = -(mean_pos - lb) + repulsion;   // EMBED_DECAY == 0
        out[0] = (float)mean_pos;
        out[1] = (float)mean_neg;
        out[2] = (float)lb;
        out[3] = (float)loss;
    }
}

extern "C" void kernel_launch(void* const* d_in, const int* in_sizes, int n_in,
                              void* d_out, int out_size, void* d_ws, size_t ws_size,
                              hipStream_t stream) {
    (void)in_sizes; (void)n_in; (void)out_size; (void)ws_size;
    const float* zx = (const float*)d_in[0];
    const float* zy = (const float*)d_in[1];
    float* out = (float*)d_out;
    char* ws = (char*)d_ws;

    float*    xx       = (float*)(ws);                        // 32 KB
    float*    yy       = (float*)(ws + (32 << 10));           // 32 KB
    float*    partials = (float*)(ws + (64 << 10));           // 64 KB
    ushort_t* xb       = (ushort_t*)(ws + (128 << 10));       // 2 MB
    ushort_t* yb       = (ushort_t*)(ws + (128 << 10) + (2 << 20)); // 2 MB

    hipLaunchKernelGGL(prep_kernel, dim3(NN / 16), dim3(256), 0, stream, zx, zy, xb, yb, xx, yy);
    hipLaunchKernelGGL(tile_kernel, dim3(NTB * NTB), dim3(512), 0, stream, xb, yb, xx, yy, partials);
    hipLaunchKernelGGL(finalize_kernel, dim3(1), dim3(256), 0, stream, partials, NTB * NTB, out);
}

// Round 3
// 43.043 us; speedup vs baseline: 2.0438x; 1.2514x over previous
//
#include <hip/hip_runtime.h>
#include <hip/hip_bf16.h>

#define NN 8192
#define DD 128
#define NTB 64       // 8192/128 tile columns
#define STRIP 8      // tiles per block (one strip)

using floatx4 = __attribute__((ext_vector_type(4))) float;
using shortx8 = __attribute__((ext_vector_type(8))) short;
typedef unsigned short ushort_t;

typedef __attribute__((address_space(1))) const unsigned GlbU32;
typedef __attribute__((address_space(3))) unsigned LdsU32;

__device__ __forceinline__ unsigned bf16pair(float lo, float hi) {
    unsigned ulo = __float_as_uint(lo);
    ulo = (ulo + 0x7FFFu + ((ulo >> 16) & 1u)) >> 16;          // RNE bf16, low half
    unsigned uhi = __float_as_uint(hi);
    uhi = (uhi + 0x7FFFu + ((uhi >> 16) & 1u)) & 0xFFFF0000u;  // RNE bf16, high half
    return uhi | ulo;
}

// ---- prep: f32 -> bf16 (row-swizzled for global_load_lds) + squared norms ----
// 16B-chunk c of row r stored at chunk position c ^ (r & 7): a LINEAR
// global_load_lds DMA then yields the XOR-swizzled LDS layout the MFMA
// fragment reads expect (both-sides-or-neither, rule #21).
__global__ void prep_kernel(const float* __restrict__ x, const float* __restrict__ y,
                            ushort_t* __restrict__ xb, ushort_t* __restrict__ yb,
                            float* __restrict__ xx, float* __restrict__ yy) {
    const int tid = threadIdx.x;
    const int r = blockIdx.x * 16 + (tid >> 4);
    const int c = tid & 15;
    const int sc = c ^ (r & 7);

    {
        const float4* xv = reinterpret_cast<const float4*>(x) + r * 32 + c * 2;
        const float4 a = xv[0], b = xv[1];
        uint4 u;
        u.x = bf16pair(a.x, a.y); u.y = bf16pair(a.z, a.w);
        u.z = bf16pair(b.x, b.y); u.w = bf16pair(b.z, b.w);
        reinterpret_cast<uint4*>(xb)[r * 16 + sc] = u;
        float s = a.x*a.x + a.y*a.y + a.z*a.z + a.w*a.w
                + b.x*b.x + b.y*b.y + b.z*b.z + b.w*b.w;
        #pragma unroll
        for (int off = 8; off; off >>= 1) s += __shfl_xor(s, off);
        if (c == 0) xx[r] = s;
    }
    {
        const float4* yv = reinterpret_cast<const float4*>(y) + r * 32 + c * 2;
        const float4 a = yv[0], b = yv[1];
        uint4 u;
        u.x = bf16pair(a.x, a.y); u.y = bf16pair(a.z, a.w);
        u.z = bf16pair(b.x, b.y); u.w = bf16pair(b.z, b.w);
        reinterpret_cast<uint4*>(yb)[r * 16 + sc] = u;
        float s = a.x*a.x + a.y*a.y + a.z*a.z + a.w*a.w
                + b.x*b.x + b.y*b.y + b.z*b.z + b.w*b.w;
        #pragma unroll
        for (int off = 8; off; off >>= 1) s += __shfl_xor(s, off);
        if (c == 0) yy[r] = s;
    }
}

// ---- strip kernel: 8 tiles of 128x128 per block, A in regs, B double-buffered ----
__global__ __launch_bounds__(512, 4) void
tile_kernel(const ushort_t* __restrict__ xb, const ushort_t* __restrict__ yb,
            const float* __restrict__ xx, const float* __restrict__ yy,
            float* __restrict__ partials) {
    __shared__ __align__(16) ushort_t Bs[2][128 * DD];   // 2 x 32 KB
    __shared__ float red[8][4];

    const int strip = blockIdx.x >> 6;     // 0..7
    const int by    = blockIdx.x & 63;     // 0..63
    const int bx0   = strip * STRIP;
    const int tid = threadIdx.x;
    const int wv = tid >> 6, lane = tid & 63;
    const int l15 = lane & 15, kq = lane >> 4;
    const int wr = (wv >> 1) * 32;   // 4 wave-row groups of 32
    const int wc = (wv & 1) * 64;    // 2 wave-col groups of 64
    const int lr = lane >> 4, lc = (lane & 15) * 8;

    // ---- DMA B tile 0 into buffer 0 (linear dest; source pre-swizzled) ----
    #pragma unroll
    for (int it = 0; it < 4; ++it) {
        const int rbase = wv * 16 + it * 4;
        const ushort_t* gb = yb + ((size_t)(bx0 * 128 + rbase) + lr) * DD + lc;
        __builtin_amdgcn_global_load_lds((GlbU32*)gb, (LdsU32*)(&Bs[0][rbase * DD]), 16, 0, 0);
    }

    // ---- A fragments: load once from pre-swizzled global, keep in VGPRs ----
    shortx8 a_reg[4][2];   // [kk][m]
    {
        const shortx8* xv = reinterpret_cast<const shortx8*>(xb);
        #pragma unroll
        for (int m = 0; m < 2; ++m) {
            const int ra = by * 128 + wr + m * 16 + l15;
            #pragma unroll
            for (int kk = 0; kk < 4; ++kk)
                a_reg[kk][m] = xv[ra * 16 + ((kk * 4 + kq) ^ (ra & 7))];
        }
    }
    // per-lane output rows: r0 + m*16 + j  (C layout: col = l15, row = kq*4+j)
    float xv1[2][4];
    const int r0 = wr + kq * 4;
    #pragma unroll
    for (int m = 0; m < 2; ++m)
        #pragma unroll
        for (int j = 0; j < 4; ++j)
            xv1[m][j] = xx[by * 128 + r0 + m * 16 + j] + 1.0f;

    float s_l2 = 0.f, s_e = 0.f, p_l2 = 0.f, p_e = 0.f;

    __syncthreads();   // drains DMA(t=0) + a_reg loads

    for (int t = 0; t < STRIP; ++t) {
        const int bx = bx0 + t;
        const int cur = t & 1;

        // prefetch next B tile into the other buffer (drained at this tile's barrier)
        if (t + 1 < STRIP) {
            #pragma unroll
            for (int it = 0; it < 4; ++it) {
                const int rbase = wv * 16 + it * 4;
                const ushort_t* gb = yb + ((size_t)((bx + 1) * 128 + rbase) + lr) * DD + lc;
                __builtin_amdgcn_global_load_lds((GlbU32*)gb, (LdsU32*)(&Bs[cur ^ 1][rbase * DD]), 16, 0, 0);
            }
        }

        // ---- MFMA over K=128 ----
        floatx4 acc[2][4];
        #pragma unroll
        for (int m = 0; m < 2; ++m)
            #pragma unroll
            for (int n = 0; n < 4; ++n)
                acc[m][n] = (floatx4){0.f, 0.f, 0.f, 0.f};

        const char* Bb = reinterpret_cast<const char*>(&Bs[cur][0]);
        #pragma unroll
        for (int kk = 0; kk < 4; ++kk) {
            shortx8 b[4];
            #pragma unroll
            for (int n = 0; n < 4; ++n) {
                const int rb = wc + n * 16 + l15;
                b[n] = *reinterpret_cast<const shortx8*>(Bb + ((rb * 256 + kk * 64 + kq * 16) ^ ((rb & 7) << 4)));
            }
            #pragma unroll
            for (int m = 0; m < 2; ++m)
                #pragma unroll
                for (int n = 0; n < 4; ++n)
                    acc[m][n] = __builtin_amdgcn_mfma_f32_16x16x32_bf16(a_reg[kk][m], b[n], acc[m][n], 0, 0, 0);
        }

        // ---- fused epilogue ----
        float yv[4];
        #pragma unroll
        for (int n = 0; n < 4; ++n) yv[n] = yy[bx * 128 + wc + n * 16 + l15];

        if (bx == by) {
            // diagonal tile: per-element logs (need individual diag logits)
            #pragma unroll
            for (int m = 0; m < 2; ++m)
                #pragma unroll
                for (int n = 0; n < 4; ++n)
                    #pragma unroll
                    for (int j = 0; j < 4; ++j) {
                        const float tt = fmaxf(fmaf(-2.0f, acc[m][n][j], xv1[m][j] + yv[n]), 1.0f);
                        const float l2 = __builtin_amdgcn_logf(tt);
                        const float e  = __builtin_amdgcn_rcpf(tt);
                        s_l2 += l2; s_e += e;
                        if (r0 + m * 16 + j == wc + n * 16 + l15) { p_l2 += l2; p_e += e; }
                    }
        } else {
            // grouped log: sum log2(t) over 8 elems = log2(prod), prod <= ~600^8 << f32 max
            #pragma unroll
            for (int m = 0; m < 2; ++m)
                #pragma unroll
                for (int half = 0; half < 2; ++half) {
                    float prod = 1.0f;
                    #pragma unroll
                    for (int dn = 0; dn < 2; ++dn) {
                        const int n = half * 2 + dn;
                        #pragma unroll
                        for (int j = 0; j < 4; ++j) {
                            const float tt = fmaxf(fmaf(-2.0f, acc[m][n][j], xv1[m][j] + yv[n]), 1.0f);
                            prod *= tt;
                            s_e += __builtin_amdgcn_rcpf(tt);
                        }
                    }
                    s_l2 += __builtin_amdgcn_logf(prod);
                }
        }
        __syncthreads();   // drains next-tile DMA; all waves done with Bs[cur]
    }

    // ---- block reduction ----
    #pragma unroll
    for (int off = 32; off; off >>= 1) {
        s_l2 += __shfl_down(s_l2, off);
        s_e  += __shfl_down(s_e,  off);
        p_l2 += __shfl_down(p_l2, off);
        p_e  += __shfl_down(p_e,  off);
    }
    if (lane == 0) {
        red[wv][0] = s_l2; red[wv][1] = s_e; red[wv][2] = p_l2; red[wv][3] = p_e;
    }
    __syncthreads();
    if (tid < 4) {
        float v = 0.f;
        #pragma unroll
        for (int w = 0; w < 8; ++w) v += red[w][tid];
        partials[blockIdx.x * 4 + tid] = v;
    }
}

// ---- final reduction + the 4 scalar outputs ----
__global__ void finalize_kernel(const float* __restrict__ partials, int nblocks,
                                float* __restrict__ out) {
    float4 v = {0.f, 0.f, 0.f, 0.f};
    for (int i = threadIdx.x; i < nblocks; i += 256) {
        const float4 p = reinterpret_cast<const float4*>(partials)[i];
        v.x += p.x; v.y += p.y; v.z += p.z; v.w += p.w;
    }
    #pragma unroll
    for (int off = 32; off; off >>= 1) {
        v.x += __shfl_down(v.x, off);
        v.y += __shfl_down(v.y, off);
        v.z += __shfl_down(v.z, off);
        v.w += __shfl_down(v.w, off);
    }
    __shared__ float red[4][4];
    const int wv = threadIdx.x >> 6, lane = threadIdx.x & 63;
    if (lane == 0) { red[wv][0] = v.x; red[wv][1] = v.y; red[wv][2] = v.z; red[wv][3] = v.w; }
    __syncthreads();
    if (threadIdx.x == 0) {
        double Sl2 = 0, Se = 0, Pl2 = 0, Pe = 0;
        for (int w = 0; w < 4; ++w) {
            Sl2 += red[w][0]; Se += red[w][1]; Pl2 += red[w][2]; Pe += red[w][3];
        }
        const double LN2 = 0.6931471805599453;
        const double Sl = -LN2 * Sl2;   // sum of logits over all pairs (natural log)
        const double Pl = -LN2 * Pl2;   // sum over diagonal
        const double Nd = (double)NN;
        const double Md = Nd * (Nd - 1.0);
        const double mean_pos = Pl / Nd;
        const double mean_neg = (Sl - Pl) / Md;
        const double sumexp_neg = Se - Pe;
        const double lb = log(sumexp_neg) - log(Md);
        const double repulsion = sumexp_neg / (Md * exp(lb));
        const double loss = -(mean_pos - lb) + repulsion;   // EMBED_DECAY == 0
        out[0] = (float)mean_pos;
        out[1] = (float)mean_neg;
        out[2] = (float)lb;
        out[3] = (float)loss;
    }
}

extern "C" void kernel_launch(void* const* d_in, const int* in_sizes, int n_in,
                              void* d_out, int out_size, void* d_ws, size_t ws_size,
                              hipStream_t stream) {
    (void)in_sizes; (void)n_in; (void)out_size; (void)ws_size;
    const float* zx = (const float*)d_in[0];
    const float* zy = (const float*)d_in[1];
    float* out = (float*)d_out;
    char* ws = (char*)d_ws;

    float*    xx       = (float*)(ws);                        // 32 KB
    float*    yy       = (float*)(ws + (32 << 10));           // 32 KB
    float*    partials = (float*)(ws + (64 << 10));           // 8 KB used
    ushort_t* xb       = (ushort_t*)(ws + (128 << 10));       // 2 MB
    ushort_t* yb       = (ushort_t*)(ws + (128 << 10) + (2 << 20)); // 2 MB

    const int nblocks = NTB * (NTB / STRIP);   // 512
    hipLaunchKernelGGL(prep_kernel, dim3(NN / 16), dim3(256), 0, stream, zx, zy, xb, yb, xx, yy);
    hipLaunchKernelGGL(tile_kernel, dim3(nblocks), dim3(512), 0, stream, xb, yb, xx, yy, partials);
    hipLaunchKernelGGL(finalize_kernel, dim3(1), dim3(256), 0, stream, partials, nblocks, out);
}